// Round 1
// baseline (96.658 us; speedup 1.0000x reference)
//
#include <hip/hip_runtime.h>

#define WAVE 64

// One wave per pair. Lane l owns DP row i=l+1 (token a[l]).
// Anti-diagonal sweep: at step t, lane l computes D[l+1][t-l+1].
//   left = own cur (step t-1)        = D[i][j-1]
//   up   = shfl_up(cur,1) (step t-1) = D[i-1][j]
//   diag = previous step's up        = D[i-1][j-1]
__global__ __launch_bounds__(256) void edit_distance_kernel(
    const int* __restrict__ t1, const int* __restrict__ t2,
    const int* __restrict__ len1, const int* __restrict__ len2,
    const float* __restrict__ subc, float* __restrict__ out, int B)
{
    const int tid  = blockIdx.x * blockDim.x + threadIdx.x;
    const int pair = tid >> 6;
    const int lane = tid & (WAVE - 1);
    if (pair >= B) return;

    const float c     = subc[0];
    const int   a_tok = t1[pair * 64 + lane];   // token for row i=lane+1
    const int   bfull = t2[pair * 64 + lane];   // b held across lanes
    const int   la    = len1[pair];
    const int   lb    = len2[pair];

    float cur   = 0.f;   // D[i][j] from previous step (valid once t >= lane)
    float upold = 0.f;   // up from previous step = D[i-1][j-1] this step
    float saved = 0.f;   // D[i][lb] snapshot

    for (int t = 0; t < 127; ++t) {
        // lane l-1's value from step t-1 -> D[i-1][j]
        float up = __shfl_up(cur, 1, WAVE);
        // b[j-1] = b[t-l], gathered from register-resident b
        int btok = __shfl(bfull, (t - lane) & 63, WAVE);

        float diag = upold;                    // lane l-1's step t-2 value
        if (lane == 0) {                       // row 0 boundary: D[0][j] = j
            up   = (float)(t + 1);             // D[0][t+1]
            diag = (float)t;                   // D[0][t]
        }
        const bool first = (t == lane);        // j == 1, need column-0 boundary
        float left = first ? (float)(lane + 1) : cur;   // D[i][0] = i
        if (first && lane > 0) diag = (float)lane;      // D[i-1][0] = i-1

        const float cost = (a_tok == btok) ? 0.f : c;
        const float v = fminf(fminf(up + 1.f, left + 1.f), diag + cost);

        const bool active = (t >= lane) && (t - lane < 64);
        const int  j = t - lane + 1;
        if (active) {
            cur = v;
            if (j == lb) saved = v;
        }
        upold = up;
    }

    // Answer lives in lane la-1 (row la), column lb snapshot.
    int src = la - 1; if (src < 0) src = 0;
    float ans = __shfl(saved, src, WAVE);
    if (la == 0)      ans = (float)lb;
    else if (lb == 0) ans = (float)la;

    if (lane == 0) out[pair] = ans;
}

extern "C" void kernel_launch(void* const* d_in, const int* in_sizes, int n_in,
                              void* d_out, int out_size, void* d_ws, size_t ws_size,
                              hipStream_t stream) {
    const int*   tokens1 = (const int*)d_in[0];
    const int*   tokens2 = (const int*)d_in[1];
    const int*   len1    = (const int*)d_in[2];
    const int*   len2    = (const int*)d_in[3];
    const float* subc    = (const float*)d_in[4];
    float*       out     = (float*)d_out;

    const int B = in_sizes[2];           // 8192
    const int threads = 256;             // 4 waves (pairs) per block
    const int blocks  = (B * WAVE + threads - 1) / threads;
    edit_distance_kernel<<<blocks, threads, 0, stream>>>(
        tokens1, tokens2, len1, len2, subc, out, B);
}

// Round 2
// 80.808 us; speedup vs baseline: 1.1962x; 1.1962x over previous
//
#include <hip/hip_runtime.h>

#define WAVE 64

__device__ __forceinline__ float bperm_f(int addr, float v) {
    return __int_as_float(__builtin_amdgcn_ds_bpermute(addr, __float_as_int(v)));
}
__device__ __forceinline__ int bperm_i(int addr, int v) {
    return __builtin_amdgcn_ds_bpermute(addr, v);
}

// One wave per pair. Lane l owns DP row i=l+1 (token a[l]).
// Anti-diagonal sweep to t < la+lb-1 only (answer cell is at t=la+lb-2).
//   left = own cur (step t-1)        = D[i][j-1]
//   up   = rot_up(cur) (step t-1)    = D[i-1][j]   (lane0 fixed up to row-0 boundary)
//   diag = previous step's up        = D[i-1][j-1]
// cur initialized to lane+1 makes the column-0 boundary emerge automatically
// at each lane's first active step (left=lane+1, diag=lane).
__global__ __launch_bounds__(256) void edit_distance_kernel(
    const int* __restrict__ t1, const int* __restrict__ t2,
    const int* __restrict__ len1, const int* __restrict__ len2,
    const float* __restrict__ subc, float* __restrict__ out, int B)
{
    const int tid  = blockIdx.x * blockDim.x + threadIdx.x;
    const int pair = tid >> 6;
    const int lane = tid & (WAVE - 1);
    if (pair >= B) return;

    const float c     = subc[0];
    const int   a_tok = t1[pair * 64 + lane];
    // Rotating register copy of b: at step t, lane l holds b[(t-l)&63].
    // Initial (t=0): lane l holds b[(-l)&63].
    int bcur = t2[pair * 64 + ((64 - lane) & 63)];
    const int la = len1[pair];
    const int lb = len2[pair];
    // Wave-uniform loop bound, scalarized.
    const int tmax = __builtin_amdgcn_readfirstlane(la + lb - 1);

    const int  rotaddr = ((lane + 63) & 63) << 2;  // pull from lane-1 (wraps)
    const bool lane0   = (lane == 0);
    const int  target  = lb + lane - 1;            // step at which j==lb for this row

    float cur   = (float)(lane + 1);  // doubles as column-0 boundary D[i][0]=i
    float diagn = 0.f;                // upold -> D[i-1][j-1]
    float saved = 0.f;                // D[i][lb] snapshot
    float ft    = 0.f;                // (float)t

    for (int t = 0; t < tmax; ++t) {
        float up   = bperm_f(rotaddr, cur);   // lane l-1's cur (lane0: garbage, fixed below)
        float diag = diagn;
        if (lane0) { up = ft + 1.f; diag = ft; }   // row-0 boundary: D[0][j]=j

        const float cost = (a_tok == bcur) ? 0.f : c;
        const float v = fminf(fminf(up, cur) + 1.f, diag + cost);

        if (t >= lane) {              // this lane's diagonal has started
            cur = v;
            if (t == target) saved = v;
        }
        diagn = up;
        bcur  = bperm_i(rotaddr, bcur);       // rotate b up by one lane
        ft   += 1.f;
    }

    int src = (la > 0) ? (la - 1) : 0;
    float ans = __shfl(saved, src, WAVE);
    if (la == 0)      ans = (float)lb;
    else if (lb == 0) ans = (float)la;

    if (lane == 0) out[pair] = ans;
}

extern "C" void kernel_launch(void* const* d_in, const int* in_sizes, int n_in,
                              void* d_out, int out_size, void* d_ws, size_t ws_size,
                              hipStream_t stream) {
    const int*   tokens1 = (const int*)d_in[0];
    const int*   tokens2 = (const int*)d_in[1];
    const int*   len1    = (const int*)d_in[2];
    const int*   len2    = (const int*)d_in[3];
    const float* subc    = (const float*)d_in[4];
    float*       out     = (float*)d_out;

    const int B = in_sizes[2];           // 8192
    const int threads = 256;             // 4 waves (pairs) per block
    const int blocks  = (B * WAVE + threads - 1) / threads;
    edit_distance_kernel<<<blocks, threads, 0, stream>>>(
        tokens1, tokens2, len1, len2, subc, out, B);
}

// Round 3
// 74.211 us; speedup vs baseline: 1.3025x; 1.0889x over previous
//
#include <hip/hip_runtime.h>

#define WAVE 64

__device__ __forceinline__ int rf(int x) { return __builtin_amdgcn_readfirstlane(x); }
__device__ __forceinline__ float bperm_f(int addr, float v) {
    return __int_as_float(__builtin_amdgcn_ds_bpermute(addr, __float_as_int(v)));
}
__device__ __forceinline__ int bperm_i(int addr, int v) {
    return __builtin_amdgcn_ds_bpermute(addr, v);
}

// One wave per pair.
// Fast path (c == 1.0): Myers' bit-parallel Levenshtein. Pattern = longer
// string (<=64 bits in one uint64), text = shorter. Eq mask per text char via
// readlane-broadcast + ballot (2 VALU ops); row update is ~20 wave-uniform
// 64-bit ops -> SALU pipe. min(la,lb) iterations (mean ~21).
// Fallback (general c): R2's anti-diagonal float DP (validated absmax=0).
__global__ __launch_bounds__(256) void edit_distance_kernel(
    const int* __restrict__ t1, const int* __restrict__ t2,
    const int* __restrict__ len1, const int* __restrict__ len2,
    const float* __restrict__ subc, float* __restrict__ out, int B)
{
    const int tid  = blockIdx.x * blockDim.x + threadIdx.x;
    const int pair = tid >> 6;
    const int lane = tid & (WAVE - 1);
    if (pair >= B) return;

    const float c      = subc[0];
    const int   a_tok  = t1[pair * 64 + lane];
    const int   b_tok  = t2[pair * 64 + lane];
    const int   la     = rf(len1[pair]);
    const int   lb     = rf(len2[pair]);
    const bool  unit_c = (rf(__float_as_int(c)) == __float_as_int(1.0f));

    if (unit_c) {
        // ---------- Myers bit-parallel path ----------
        const bool sw  = lb > la;
        const int  m   = sw ? lb : la;      // pattern length (max)
        const int  n   = sw ? la : lb;      // text length (min)
        const int  pat = sw ? b_tok : a_tok;  // lane i holds pattern[i]
        const int  txt = sw ? a_tok : b_tok;  // lane j holds text[j]

        float ans;
        if (m == 0) {
            ans = 0.f;                      // both empty
        } else {
            unsigned long long Pv = ~0ull, Mv = 0ull;
            int score    = m;
            const int hs = m - 1;           // high bit position
            for (int j = 0; j < n; ++j) {
                const int bj = __builtin_amdgcn_readlane(txt, j);
                unsigned long long Eq = __ballot(pat == bj);  // bit i: pattern[i]==text[j]
                unsigned long long Xv = Eq | Mv;
                unsigned long long Xh = (((Eq & Pv) + Pv) ^ Pv) | Eq;
                unsigned long long Ph = Mv | ~(Xh | Pv);
                unsigned long long Mh = Pv & Xh;
                score += (int)((Ph >> hs) & 1ull);
                score -= (int)((Mh >> hs) & 1ull);
                Ph = (Ph << 1) | 1ull;
                Pv = (Mh << 1) | ~(Xv | Ph);
                Mv = Ph & Xv;
            }
            ans = (float)score;
        }
        if (lane == 0) out[pair] = ans;
    } else {
        // ---------- general-cost anti-diagonal DP (R2) ----------
        const int rotaddr = ((lane + 63) & 63) << 2;
        int bcur = bperm_i(((64 - lane) & 63) << 2, b_tok);  // lane l: b[(-l)&63]
        const int  tmax   = rf(la + lb - 1);
        const bool lane0  = (lane == 0);
        const int  target = lb + lane - 1;

        float cur   = (float)(lane + 1);
        float diagn = 0.f;
        float saved = 0.f;
        float ft    = 0.f;

        for (int t = 0; t < tmax; ++t) {
            float up   = bperm_f(rotaddr, cur);
            float diag = diagn;
            if (lane0) { up = ft + 1.f; diag = ft; }

            const float cost = (a_tok == bcur) ? 0.f : c;
            const float v = fminf(fminf(up, cur) + 1.f, diag + cost);

            if (t >= lane) {
                cur = v;
                if (t == target) saved = v;
            }
            diagn = up;
            bcur  = bperm_i(rotaddr, bcur);
            ft   += 1.f;
        }

        int src = (la > 0) ? (la - 1) : 0;
        float ans = __shfl(saved, src, WAVE);
        if (la == 0)      ans = (float)lb;
        else if (lb == 0) ans = (float)la;

        if (lane == 0) out[pair] = ans;
    }
}

extern "C" void kernel_launch(void* const* d_in, const int* in_sizes, int n_in,
                              void* d_out, int out_size, void* d_ws, size_t ws_size,
                              hipStream_t stream) {
    const int*   tokens1 = (const int*)d_in[0];
    const int*   tokens2 = (const int*)d_in[1];
    const int*   len1    = (const int*)d_in[2];
    const int*   len2    = (const int*)d_in[3];
    const float* subc    = (const float*)d_in[4];
    float*       out     = (float*)d_out;

    const int B = in_sizes[2];           // 8192
    const int threads = 256;             // 4 waves (pairs) per block
    const int blocks  = (B * WAVE + threads - 1) / threads;
    edit_distance_kernel<<<blocks, threads, 0, stream>>>(
        tokens1, tokens2, len1, len2, subc, out, B);
}

// Round 4
// 69.894 us; speedup vs baseline: 1.3829x; 1.0618x over previous
//
#include <hip/hip_runtime.h>

#define WAVE 64

__device__ __forceinline__ int rf(int x) { return __builtin_amdgcn_readfirstlane(x); }
__device__ __forceinline__ float bperm_f(int addr, float v) {
    return __int_as_float(__builtin_amdgcn_ds_bpermute(addr, __float_as_int(v)));
}
__device__ __forceinline__ int bperm_i(int addr, int v) {
    return __builtin_amdgcn_ds_bpermute(addr, v);
}

// One wave per pair.
// Fast path (c == 1.0): Myers' bit-parallel Levenshtein, two exact reductions:
//  (1) no per-iter score: final column deltas give
//      score = n + pcnt(Pv & lowmask(m)) - pcnt(Mv & lowmask(m))
//  (2) sparse step: when (Eq|Mv)==0 (≈99.4% of iters for V=10000 random
//      tokens) the update collapses exactly to Pv <<= 1 (Mv stays 0).
// Inner loop ≈ 2 VALU (readlane + ballot cmp) + ~7 SALU, wave-uniform branch.
// Fallback (general c): R2's anti-diagonal float DP (validated absmax=0).
__global__ __launch_bounds__(256) void edit_distance_kernel(
    const int* __restrict__ t1, const int* __restrict__ t2,
    const int* __restrict__ len1, const int* __restrict__ len2,
    const float* __restrict__ subc, float* __restrict__ out, int B)
{
    const int tid  = blockIdx.x * blockDim.x + threadIdx.x;
    const int pair = tid >> 6;
    const int lane = tid & (WAVE - 1);
    if (pair >= B) return;

    const float c      = subc[0];
    const int   a_tok  = t1[pair * 64 + lane];
    const int   b_tok  = t2[pair * 64 + lane];
    const int   la     = rf(len1[pair]);
    const int   lb     = rf(len2[pair]);
    const bool  unit_c = (rf(__float_as_int(c)) == __float_as_int(1.0f));

    if (unit_c) {
        // ---------- Myers bit-parallel, scalar-pipe resident ----------
        const bool sw  = lb > la;
        const int  m   = sw ? lb : la;        // pattern length (max, <=63)
        const int  n   = sw ? la : lb;        // text length (min)
        const int  pat = sw ? b_tok : a_tok;  // lane i holds pattern[i]
        const int  txt = sw ? a_tok : b_tok;  // lane j holds text[j]

        unsigned long long Pv = ~0ull, Mv = 0ull;
        for (int j = 0; j < n; ++j) {
            const int bj = __builtin_amdgcn_readlane(txt, j);
            const unsigned long long Eq = __ballot(pat == bj);
            if ((Eq | Mv) == 0ull) {
                Pv <<= 1;                     // exact collapsed update
            } else {
                const unsigned long long Xv = Eq | Mv;
                const unsigned long long Xh = (((Eq & Pv) + Pv) ^ Pv) | Eq;
                unsigned long long Ph = Mv | ~(Xh | Pv);
                const unsigned long long Mh = Pv & Xh;
                Ph = (Ph << 1) | 1ull;
                Pv = (Mh << 1) | ~(Xv | Ph);
                Mv = Ph & Xv;
            }
        }
        const unsigned long long mask = (m == 0) ? 0ull : (~0ull >> (64 - m));
        const int score = n + __popcll(Pv & mask) - __popcll(Mv & mask);
        if (lane == 0) out[pair] = (float)score;
    } else {
        // ---------- general-cost anti-diagonal DP (R2) ----------
        const int rotaddr = ((lane + 63) & 63) << 2;
        int bcur = bperm_i(((64 - lane) & 63) << 2, b_tok);
        const int  tmax   = rf(la + lb - 1);
        const bool lane0  = (lane == 0);
        const int  target = lb + lane - 1;

        float cur   = (float)(lane + 1);
        float diagn = 0.f;
        float saved = 0.f;
        float ft    = 0.f;

        for (int t = 0; t < tmax; ++t) {
            float up   = bperm_f(rotaddr, cur);
            float diag = diagn;
            if (lane0) { up = ft + 1.f; diag = ft; }

            const float cost = (a_tok == bcur) ? 0.f : c;
            const float v = fminf(fminf(up, cur) + 1.f, diag + cost);

            if (t >= lane) {
                cur = v;
                if (t == target) saved = v;
            }
            diagn = up;
            bcur  = bperm_i(rotaddr, bcur);
            ft   += 1.f;
        }

        int src = (la > 0) ? (la - 1) : 0;
        float ans = __shfl(saved, src, WAVE);
        if (la == 0)      ans = (float)lb;
        else if (lb == 0) ans = (float)la;

        if (lane == 0) out[pair] = ans;
    }
}

extern "C" void kernel_launch(void* const* d_in, const int* in_sizes, int n_in,
                              void* d_out, int out_size, void* d_ws, size_t ws_size,
                              hipStream_t stream) {
    const int*   tokens1 = (const int*)d_in[0];
    const int*   tokens2 = (const int*)d_in[1];
    const int*   len1    = (const int*)d_in[2];
    const int*   len2    = (const int*)d_in[3];
    const float* subc    = (const float*)d_in[4];
    float*       out     = (float*)d_out;

    const int B = in_sizes[2];           // 8192
    const int threads = 256;             // 4 waves (pairs) per block
    const int blocks  = (B * WAVE + threads - 1) / threads;
    edit_distance_kernel<<<blocks, threads, 0, stream>>>(
        tokens1, tokens2, len1, len2, subc, out, B);
}